// Round 13
// baseline (32.582 us; speedup 1.0000x reference)
//
#include <hip/hip_runtime.h>

#define B_N   2048
#define LQ    10
#define LH    150

typedef float pf2 __attribute__((ext_vector_type(2)));

// ws float layout:
//   [0..17]   eff_w (ch*9+ky*3+kx)     [18] eff_b      [19..27] fw
//   [30..119] qwpk: float2[45]  {q_w[2ap][t], q_w[2ap+1][t]}, idx=ap*9+t
//   [120..209] wpk: float2[45]  {w[2ap][t],  w[2ap+1][t]},   idx=ap*9+t
#define QWPK 30
#define WPK  120

// ---------------- pre-kernel: wide (1 block x 256 thr) ----------------
__global__ __launch_bounds__(256) void vin_precompute(
    const float* __restrict__ h_w, const float* __restrict__ h_b,
    const float* __restrict__ r_w, const float* __restrict__ q_w,
    const float* __restrict__ w,   const float* __restrict__ fc_w,
    float* __restrict__ ws)
{
    const int lane = threadIdx.x;
    if (lane < 152) {
        const int t = lane >> 3, j = lane & 7;
        float part = 0.f;
        if (t < 18) { for (int h = j; h < LH; h += 8) part += r_w[h] * h_w[h * 18 + t]; }
        else        { for (int h = j; h < LH; h += 8) part += r_w[h] * h_b[h]; }
        part += __shfl_down(part, 4, 8);
        part += __shfl_down(part, 2, 8);
        part += __shfl_down(part, 1, 8);
        if (j == 0) ws[t] = part;
    } else if (lane >= 152 && lane < 161) {
        const int t = lane - 152;
        float acc = 0.f;
        #pragma unroll
        for (int a = 0; a < LQ; ++a) acc += fc_w[a] * w[a * 9 + t];
        ws[19 + t] = acc;
    } else if (lane >= 161 && lane < 206) {
        const int idx = lane - 161, ap = idx / 9, t = idx - ap * 9;
        ws[QWPK + 2 * idx]     = q_w[(2 * ap)     * 9 + t];
        ws[QWPK + 2 * idx + 1] = q_w[(2 * ap + 1) * 9 + t];
    } else if (lane >= 206 && lane < 251) {
        const int idx = lane - 206, ap = idx / 9, t = idx - ap * 9;
        ws[WPK + 2 * idx]     = w[(2 * ap)     * 9 + t];
        ws[WPK + 2 * idx + 1] = w[(2 * ap + 1) * 9 + t];
    }
}

// ---------------- main kernel ----------------
// 256 threads = 1 batch element/block, 1 PIXEL/LANE (tid = i*16+c), 2048
// blocks -> 8 blocks/CU = ~32 waves/CU (R12's 1024-block grid capped
// residency at 4 blocks/CU = 50% of wave slots; all evidence since R8 says
// we're stall-bound, so resident waves are the lever).
// __launch_bounds__(256,4) NOT (256,8): the 2nd arg is an allocator floor
// (VGPR cap 128), not an occupancy ceiling -- actual VGPR ~40 lets HW run
// 8 blocks/CU anyway, while (256,8)'s hard caps caused R9's remat disaster.
//
// LDS arena (2160 floats, ROW STRIDE 40: for fixed tap, 4 rows/wave hit
// banks {0,8,16,24}+c -> max 2-way aliasing, free per m136):
//   XS [0,1440)    : padded X, ch*720 + (row+1)*40 + (col+1)
//   VP [0,1440)    : double-buffered padded v -- ALIASES dead X (interior-
//                    only writes keep the zeroed borders intact)
//   RP [1440,2160) : padded r
// VI inner loop: action-pair packed fp32 (v_pk_fma_f32 + v_pk_max_f32),
// weights via uniform s_loads. No runtime indexing into register arrays.
#define ST    40
#define RPOF  1440
#define VB    720
#define SMEMN 2160

__global__ __launch_bounds__(256, 4) void vin_kernel(
    const float* __restrict__ X,   const float* __restrict__ S1,
    const float* __restrict__ S2,  const float* __restrict__ fcw,
    const float* __restrict__ ws,  float* __restrict__ out)
{
    __shared__ float smem[SMEMN];

    const int tid = threadIdx.x;
    const int i   = tid >> 4;     // pixel row 0..15
    const int c   = tid & 15;     // pixel col 0..15
    const int b   = blockIdx.x;

    // ---- issue X loads first ----
    const float* Xb = X + (size_t)b * 512;
    float x0 = Xb[tid], x1 = Xb[tid + 256];

    // ---- collapsed weights via uniform s_loads ----
    float ew[19];
    #pragma unroll
    for (int tt = 0; tt < 19; ++tt) ew[tt] = ws[tt];

    // ---- zero arena (conv borders must be 0) ----
    #pragma unroll
    for (int k = 0; k < 9; ++k) {
        int idx = tid + (k << 8);
        if (idx < SMEMN) smem[idx] = 0.f;
    }
    __syncthreads();

    // ---- stage X (interior cells only) ----
    smem[      (i + 1) * ST + c + 1] = x0;
    smem[720 + (i + 1) * ST + c + 1] = x1;
    __syncthreads();

    // ---- r = conv3x3(X, eff_w) + eff_b ----
    {
        float acc = ew[18];
        const float* xb = smem + i * ST + c;
        #pragma unroll
        for (int ch = 0; ch < 2; ++ch)
            #pragma unroll
            for (int ky = 0; ky < 3; ++ky)
                #pragma unroll
                for (int kx = 0; kx < 3; ++kx)
                    acc += xb[ch * 720 + ky * ST + kx] * ew[ch * 9 + ky * 3 + kx];
        smem[RPOF + (i + 1) * ST + c + 1] = acc;
    }
    __syncthreads();

    // ---- qr2[ap] = packed conv3x3(r, q_w) for action pair ap ----
    float rt[3][3];
    {
        const float* rb = smem + RPOF + i * ST + c;
        #pragma unroll
        for (int ky = 0; ky < 3; ++ky)
            #pragma unroll
            for (int kx = 0; kx < 3; ++kx)
                rt[ky][kx] = rb[ky * ST + kx];
    }

    const pf2* qwp = (const pf2*)(ws + QWPK);
    const pf2* wpk = (const pf2*)(ws + WPK);

    pf2 qr2[5];
    #pragma unroll
    for (int ap = 0; ap < 5; ++ap) {
        pf2 acc = {0.f, 0.f};
        #pragma unroll
        for (int tt = 0; tt < 9; ++tt) {
            const float tap = rt[tt / 3][tt % 3];
            pf2 ts = {tap, tap};
            acc = __builtin_elementwise_fma(ts, qwp[ap * 9 + tt], acc);
        }
        qr2[ap] = acc;
    }

    // ---- v0 = max over 10 actions (pk_max tree) ----
    {
        pf2 mv = __builtin_elementwise_max(
                     __builtin_elementwise_max(qr2[0], qr2[1]),
                     __builtin_elementwise_max(qr2[2], qr2[3]));
        mv = __builtin_elementwise_max(mv, qr2[4]);
        smem[(i + 1) * ST + c + 1] = fmaxf(mv.x, mv.y);
    }
    __syncthreads();

    // ---- 19 VI sweeps: 9 taps, 45 pk_fma, pk_max tree, 1 barrier/step ----
#define VSTEP(SRC, DST)                                                        \
    {                                                                          \
        const float* vb = smem + (SRC) + i * ST + c;                           \
        float vt[3][3];                                                        \
        _Pragma("unroll")                                                      \
        for (int ky = 0; ky < 3; ++ky)                                         \
            _Pragma("unroll")                                                  \
            for (int kx = 0; kx < 3; ++kx)                                     \
                vt[ky][kx] = vb[ky * ST + kx];                                 \
        pf2 a_[5];                                                             \
        _Pragma("unroll")                                                      \
        for (int ap = 0; ap < 5; ++ap) a_[ap] = qr2[ap];                       \
        _Pragma("unroll")                                                      \
        for (int tt = 0; tt < 9; ++tt) {                                       \
            const float tap = vt[tt / 3][tt % 3];                              \
            pf2 ts = {tap, tap};                                               \
            _Pragma("unroll")                                                  \
            for (int ap = 0; ap < 5; ++ap)                                     \
                a_[ap] = __builtin_elementwise_fma(ts, wpk[ap * 9 + tt], a_[ap]); \
        }                                                                      \
        pf2 mv = __builtin_elementwise_max(                                    \
                     __builtin_elementwise_max(a_[0], a_[1]),                  \
                     __builtin_elementwise_max(a_[2], a_[3]));                 \
        mv = __builtin_elementwise_max(mv, a_[4]);                             \
        smem[(DST) + (i + 1) * ST + c + 1] = fmaxf(mv.x, mv.y);                \
        __syncthreads();                                                       \
    }

    #pragma unroll 1
    for (int it = 0; it < 9; ++it) {
        VSTEP(0, VB)
        VSTEP(VB, 0)
    }
    VSTEP(0, VB)   // step 19; final v in smem+VB

    // ---- final conv + gather + fc at (s1, s2) only ----
    const float s1f = S1[b], s2f = S2[b];
    int s1 = (int)floorf((s1f + 50.0f) / 6.25f);
    int s2 = (int)floorf((s2f + 50.0f) / 6.25f);
    s1 = min(max(s1, 0), 15);
    s2 = min(max(s2, 0), 15);

    if (i == s1 && c == s2) {
        float logit = 0.f;
        #pragma unroll
        for (int ap = 0; ap < 5; ++ap)
            logit += fcw[2 * ap] * qr2[ap].x + fcw[2 * ap + 1] * qr2[ap].y;
        #pragma unroll
        for (int ky = 0; ky < 3; ++ky)
            #pragma unroll
            for (int kx = 0; kx < 3; ++kx)
                logit += smem[VB + (s1 + ky) * ST + s2 + kx]
                       * ws[19 + ky * 3 + kx];
        out[b]       = logit;   // logits
        out[B_N + b] = 1.0f;    // softmax over length-1 axis == 1
    }
#undef VSTEP
}

extern "C" void kernel_launch(void* const* d_in, const int* in_sizes, int n_in,
                              void* d_out, int out_size, void* d_ws, size_t ws_size,
                              hipStream_t stream) {
    const float* X    = (const float*)d_in[0];
    const float* S1   = (const float*)d_in[1];
    const float* S2   = (const float*)d_in[2];
    const float* h_w  = (const float*)d_in[3];
    const float* h_b  = (const float*)d_in[4];
    const float* r_w  = (const float*)d_in[5];
    const float* q_w  = (const float*)d_in[6];
    const float* w    = (const float*)d_in[7];
    const float* fc_w = (const float*)d_in[8];
    float*       out  = (float*)d_out;
    float*       ws   = (float*)d_ws;

    vin_precompute<<<1, 256, 0, stream>>>(h_w, h_b, r_w, q_w, w, fc_w, ws);
    vin_kernel<<<B_N, 256, 0, stream>>>(X, S1, S2, fc_w, ws, out);
}

// Round 14
// 30.313 us; speedup vs baseline: 1.0749x; 1.0749x over previous
//
#include <hip/hip_runtime.h>

#define B_N   2048
#define LQ    10
#define LH    150

typedef float pf2 __attribute__((ext_vector_type(2)));

// ws float layout:
//   [0..17]   eff_w (ch*9+ky*3+kx)     [18] eff_b      [19..27] fw
//   [30..119] qwpk: float2[45]  {q_w[2ap][t], q_w[2ap+1][t]}, idx=ap*9+t
//   [120..209] wpk: float2[45]  {w[2ap][t],  w[2ap+1][t]},   idx=ap*9+t
#define QWPK 30
#define WPK  120

// ---------------- pre-kernel: wide (1 block x 256 thr) ----------------
__global__ __launch_bounds__(256) void vin_precompute(
    const float* __restrict__ h_w, const float* __restrict__ h_b,
    const float* __restrict__ r_w, const float* __restrict__ q_w,
    const float* __restrict__ w,   const float* __restrict__ fc_w,
    float* __restrict__ ws)
{
    const int lane = threadIdx.x;
    if (lane < 152) {
        const int t = lane >> 3, j = lane & 7;
        float part = 0.f;
        if (t < 18) { for (int h = j; h < LH; h += 8) part += r_w[h] * h_w[h * 18 + t]; }
        else        { for (int h = j; h < LH; h += 8) part += r_w[h] * h_b[h]; }
        part += __shfl_down(part, 4, 8);
        part += __shfl_down(part, 2, 8);
        part += __shfl_down(part, 1, 8);
        if (j == 0) ws[t] = part;
    } else if (lane >= 152 && lane < 161) {
        const int t = lane - 152;
        float acc = 0.f;
        #pragma unroll
        for (int a = 0; a < LQ; ++a) acc += fc_w[a] * w[a * 9 + t];
        ws[19 + t] = acc;
    } else if (lane >= 161 && lane < 206) {
        const int idx = lane - 161, ap = idx / 9, t = idx - ap * 9;
        ws[QWPK + 2 * idx]     = q_w[(2 * ap)     * 9 + t];
        ws[QWPK + 2 * idx + 1] = q_w[(2 * ap + 1) * 9 + t];
    } else if (lane >= 206 && lane < 251) {
        const int idx = lane - 206, ap = idx / 9, t = idx - ap * 9;
        ws[WPK + 2 * idx]     = w[(2 * ap)     * 9 + t];
        ws[WPK + 2 * idx + 1] = w[(2 * ap + 1) * 9 + t];
    }
}

// ---------------- main kernel ----------------
// ONE WAVE per batch element (2048 blocks x 64 thr = 8 single-wave blocks/CU,
// 2 waves/SIMD). lane = rg*16 + c; rg owns pixel rows 4rg..4rg+3, col c.
//
// VI loop is REGISTER-RESIDENT and BARRIER-FREE (R13 showed TLP saturated;
// the wall is the per-step LDS round-trip + barrier). R7's shuffle version
// lost to 14 LDS-pipe ops + 24 masks + scalar FMA; fixed here:
//   - horizontal halo via DPP row_shr:1/row_shl:1 (16-lane DPP rows == our
//     column dim; bound_ctrl zeroes row-edge lanes = free zero padding):
//     12 VALU ops, no LDS, no masks
//   - vertical halo: only 2 ds_bpermute (+2 cndmask for grid top/bottom)
//   - action-pair packed fp32 (R12's v_pk_fma_f32, weights = SGPR pairs):
//     180 pk_fma per lane-step
// LDS (prologue only, ROW STRIDE 36: 4rg*36 -> banks {0,16,0,16}+c, 2-way
// = free):  XS [0,1296) padded X (ch*648), RP [1296,1944) padded r.
// No runtime indexing into register arrays (round-4 lesson).
#define ST    36
#define RPOF  1296
#define SMEMN 1944

__device__ __forceinline__ float dpp_left(float x) {   // value from col c-1; 0 at c==0
    return __int_as_float(__builtin_amdgcn_update_dpp(
        0, __float_as_int(x), 0x111, 0xF, 0xF, true));  // row_shr:1
}
__device__ __forceinline__ float dpp_right(float x) {  // value from col c+1; 0 at c==15
    return __int_as_float(__builtin_amdgcn_update_dpp(
        0, __float_as_int(x), 0x101, 0xF, 0xF, true));  // row_shl:1
}

__global__ __launch_bounds__(64, 2) void vin_kernel(
    const float* __restrict__ X,   const float* __restrict__ S1,
    const float* __restrict__ S2,  const float* __restrict__ fcw,
    const float* __restrict__ ws,  float* __restrict__ out)
{
    __shared__ float smem[SMEMN];

    const int lane = threadIdx.x;
    const int rg   = lane >> 4;
    const int c    = lane & 15;
    const int b    = blockIdx.x;

    // ---- issue all global loads first ----
    const float* Xb = X + (size_t)b * 512;
    float xreg[8];
    #pragma unroll
    for (int k = 0; k < 8; ++k) xreg[k] = Xb[lane + (k << 6)];
    const float s1f = S1[b], s2f = S2[b];

    // ---- zero arena (conv borders must be 0) ----
    #pragma unroll
    for (int k = 0; k < 31; ++k) {
        int idx = lane + (k << 6);
        if (idx < SMEMN) smem[idx] = 0.f;
    }

    // ---- collapsed weights via uniform s_loads ----
    float ew[19];
    #pragma unroll
    for (int tt = 0; tt < 19; ++tt) ew[tt] = ws[tt];
    __syncthreads();

    // ---- stage X (interior cells only) ----
    #pragma unroll
    for (int k = 0; k < 8; ++k) {
        int e = lane + (k << 6);
        int ch = e >> 8, rem = e & 255;
        smem[ch * 648 + ((rem >> 4) + 1) * ST + (rem & 15) + 1] = xreg[k];
    }
    __syncthreads();

    // ---- r = conv3x3(X, eff_w) + eff_b for this lane's 4 rows ----
    {
        const float* xb = smem + (rg << 2) * ST + c;
        float xt[2][6][3];
        #pragma unroll
        for (int ch = 0; ch < 2; ++ch)
            #pragma unroll
            for (int dy = 0; dy < 6; ++dy)
                #pragma unroll
                for (int dx = 0; dx < 3; ++dx)
                    xt[ch][dy][dx] = xb[ch * 648 + dy * ST + dx];

        #pragma unroll
        for (int k = 0; k < 4; ++k) {
            float acc = ew[18];
            #pragma unroll
            for (int ch = 0; ch < 2; ++ch)
                #pragma unroll
                for (int ky = 0; ky < 3; ++ky)
                    #pragma unroll
                    for (int kx = 0; kx < 3; ++kx)
                        acc += xt[ch][k + ky][kx] * ew[ch * 9 + ky * 3 + kx];
            smem[RPOF + ((rg << 2) + k + 1) * ST + c + 1] = acc;
        }
    }
    __syncthreads();

    // ---- qr2[k][ap] = packed conv3x3(r, q_w) (iteration-invariant) ----
    float rt[6][3];
    {
        const float* rb = smem + RPOF + (rg << 2) * ST + c;
        #pragma unroll
        for (int dy = 0; dy < 6; ++dy)
            #pragma unroll
            for (int dx = 0; dx < 3; ++dx)
                rt[dy][dx] = rb[dy * ST + dx];
    }

    const pf2* qwp = (const pf2*)(ws + QWPK);
    const pf2* wpk = (const pf2*)(ws + WPK);

    pf2 qr2[4][5];
    #pragma unroll
    for (int k = 0; k < 4; ++k)
        #pragma unroll
        for (int ap = 0; ap < 5; ++ap) {
            pf2 acc = {0.f, 0.f};
            #pragma unroll
            for (int tt = 0; tt < 9; ++tt) {
                const float tap = rt[k + tt / 3][tt % 3];
                pf2 ts = {tap, tap};
                acc = __builtin_elementwise_fma(ts, qwp[ap * 9 + tt], acc);
            }
            qr2[k][ap] = acc;
        }

    // ---- v0 = max over 10 actions, register-resident ----
    float vv0, vv1, vv2, vv3;
    {
        pf2 m0 = __builtin_elementwise_max(
                     __builtin_elementwise_max(qr2[0][0], qr2[0][1]),
                     __builtin_elementwise_max(qr2[0][2], qr2[0][3]));
        m0 = __builtin_elementwise_max(m0, qr2[0][4]);
        vv0 = fmaxf(m0.x, m0.y);
        pf2 m1 = __builtin_elementwise_max(
                     __builtin_elementwise_max(qr2[1][0], qr2[1][1]),
                     __builtin_elementwise_max(qr2[1][2], qr2[1][3]));
        m1 = __builtin_elementwise_max(m1, qr2[1][4]);
        vv1 = fmaxf(m1.x, m1.y);
        pf2 m2 = __builtin_elementwise_max(
                     __builtin_elementwise_max(qr2[2][0], qr2[2][1]),
                     __builtin_elementwise_max(qr2[2][2], qr2[2][3]));
        m2 = __builtin_elementwise_max(m2, qr2[2][4]);
        vv2 = fmaxf(m2.x, m2.y);
        pf2 m3 = __builtin_elementwise_max(
                     __builtin_elementwise_max(qr2[3][0], qr2[3][1]),
                     __builtin_elementwise_max(qr2[3][2], qr2[3][3]));
        m3 = __builtin_elementwise_max(m3, qr2[3][4]);
        vv3 = fmaxf(m3.x, m3.y);
    }

    const bool top0 = (rg == 0), bot0 = (rg == 3);
    const int  upL  = (lane - 16) & 63;
    const int  dnL  = (lane + 16) & 63;

    float S[6], L[6], R[6];
    // S[j] = own-column v at pixel row 4rg-1+j; L/R = cols c-1/c+1 via DPP.
#define HALO()                                                       \
    {                                                                \
        float t_ = __shfl(vv3, upL, 64);                             \
        float b_ = __shfl(vv0, dnL, 64);                             \
        S[0] = top0 ? 0.f : t_;                                      \
        S[1] = vv0; S[2] = vv1; S[3] = vv2; S[4] = vv3;              \
        S[5] = bot0 ? 0.f : b_;                                      \
        _Pragma("unroll")                                            \
        for (int j = 0; j < 6; ++j) {                                \
            L[j] = dpp_left(S[j]);                                   \
            R[j] = dpp_right(S[j]);                                  \
        }                                                            \
    }

    // ---- 19 VI sweeps: barrier-free, LDS-free, packed fp32 ----
    #pragma unroll 1
    for (int it = 0; it < 19; ++it) {
        HALO();
        #pragma unroll
        for (int k = 0; k < 4; ++k) {
            pf2 a_[5];
            #pragma unroll
            for (int ap = 0; ap < 5; ++ap) a_[ap] = qr2[k][ap];
            #pragma unroll
            for (int dy = 0; dy < 3; ++dy) {
                const float tl = L[k + dy], ts = S[k + dy], tr = R[k + dy];
                pf2 vl = {tl, tl}, vs = {ts, ts}, vr = {tr, tr};
                #pragma unroll
                for (int ap = 0; ap < 5; ++ap) {
                    a_[ap] = __builtin_elementwise_fma(vl, wpk[ap * 9 + dy * 3 + 0], a_[ap]);
                    a_[ap] = __builtin_elementwise_fma(vs, wpk[ap * 9 + dy * 3 + 1], a_[ap]);
                    a_[ap] = __builtin_elementwise_fma(vr, wpk[ap * 9 + dy * 3 + 2], a_[ap]);
                }
            }
            pf2 m = __builtin_elementwise_max(
                        __builtin_elementwise_max(a_[0], a_[1]),
                        __builtin_elementwise_max(a_[2], a_[3]));
            m = __builtin_elementwise_max(m, a_[4]);
            float mk = fmaxf(m.x, m.y);
            if (k == 0) vv0 = mk; else if (k == 1) vv1 = mk;
            else if (k == 2) vv2 = mk; else vv3 = mk;
        }
    }

    // ---- one more halo for the final conv's v-taps ----
    HALO();

    // ---- final conv + gather + fc at (s1, s2) only ----
    int s1 = (int)floorf((s1f + 50.0f) / 6.25f);
    int s2 = (int)floorf((s2f + 50.0f) / 6.25f);
    s1 = min(max(s1, 0), 15);
    s2 = min(max(s2, 0), 15);

    if (rg == (s1 >> 2) && c == s2) {
        float fw[9];
        #pragma unroll
        for (int tt = 0; tt < 9; ++tt) fw[tt] = ws[19 + tt];

        float d0, d1, d2, d3;
        {
            pf2 p0 = {0.f, 0.f}, p1 = p0, p2 = p0, p3 = p0;
            #pragma unroll
            for (int ap = 0; ap < 5; ++ap) {
                const pf2 fcp = *(const pf2*)(fcw + 2 * ap);
                p0 = __builtin_elementwise_fma(qr2[0][ap], fcp, p0);
                p1 = __builtin_elementwise_fma(qr2[1][ap], fcp, p1);
                p2 = __builtin_elementwise_fma(qr2[2][ap], fcp, p2);
                p3 = __builtin_elementwise_fma(qr2[3][ap], fcp, p3);
            }
            d0 = p0.x + p0.y; d1 = p1.x + p1.y;
            d2 = p2.x + p2.y; d3 = p3.x + p3.y;
        }
        float g0 = d0, g1 = d1, g2 = d2, g3 = d3;
        #pragma unroll
        for (int dy = 0; dy < 3; ++dy) {
            const float f0 = fw[dy * 3 + 0], f1 = fw[dy * 3 + 1], f2 = fw[dy * 3 + 2];
            g0 += L[0 + dy] * f0; g0 += S[0 + dy] * f1; g0 += R[0 + dy] * f2;
            g1 += L[1 + dy] * f0; g1 += S[1 + dy] * f1; g1 += R[1 + dy] * f2;
            g2 += L[2 + dy] * f0; g2 += S[2 + dy] * f1; g2 += R[2 + dy] * f2;
            g3 += L[3 + dy] * f0; g3 += S[3 + dy] * f1; g3 += R[3 + dy] * f2;
        }
        const int kk = s1 & 3;
        float logit = (kk == 0) ? g0 : (kk == 1) ? g1 : (kk == 2) ? g2 : g3;
        out[b]       = logit;   // logits
        out[B_N + b] = 1.0f;    // softmax over length-1 axis == 1
    }
#undef HALO
}

extern "C" void kernel_launch(void* const* d_in, const int* in_sizes, int n_in,
                              void* d_out, int out_size, void* d_ws, size_t ws_size,
                              hipStream_t stream) {
    const float* X    = (const float*)d_in[0];
    const float* S1   = (const float*)d_in[1];
    const float* S2   = (const float*)d_in[2];
    const float* h_w  = (const float*)d_in[3];
    const float* h_b  = (const float*)d_in[4];
    const float* r_w  = (const float*)d_in[5];
    const float* q_w  = (const float*)d_in[6];
    const float* w    = (const float*)d_in[7];
    const float* fc_w = (const float*)d_in[8];
    float*       out  = (float*)d_out;
    float*       ws   = (float*)d_ws;

    vin_precompute<<<1, 256, 0, stream>>>(h_w, h_b, r_w, q_w, w, fc_w, ws);
    vin_kernel<<<B_N, 64, 0, stream>>>(X, S1, S2, fc_w, ws, out);
}